// Round 15
// baseline (386.407 us; speedup 1.0000x reference)
//
#include <hip/hip_runtime.h>
#include <hip/hip_bf16.h>

#define DIM  1024
#define HID  2816
#define NE   8
#define NTOK 4096
#define NPAIR 8192
#define CAP  8192

#define NT_UPX (HID / 128)          // 22 GEMM N-tiles in up grid.x
#define NT_DN (DIM / 128)           // 8 N-tiles (down)
#define MT    (CAP / 128)           // 64 M-tiles
#define NWG_DN (NE * NT_DN * MT)    // 4096

#define WELEM ((size_t)NE * DIM * HID)

typedef __bf16 bf16x8 __attribute__((ext_vector_type(8)));
typedef float f32x4 __attribute__((ext_vector_type(4)));

// ---------------- workspace layout ----------------
#define OFF_CNT  0                         // 8 ints
#define OFF_LIST 1024                      // NE*CAP ints  = 256 KB
#define OFF_WP   (OFF_LIST + NE*CAP*4)     // NPAIR floats = 32 KB
// fallback path
#define OFF_H1   (OFF_WP + NPAIR*4)
// fast path (r9-proven)
#define OFF_XB   ((size_t)1 << 20)                  // 8 MB   (NTOK*DIM bf16)
#define OFF_W1B  ((size_t)10 << 20)                 // 46.14 MB; reused for W2b (mid-ws)
#define OFF_W3B  ((size_t)57 << 20)                 // 46.14 MB; reused for Obuf after up
#define OFF_H2   ((size_t)106 << 20)                // 46.14 MB (NPAIR*HID bf16)
#define WS_NEED  (OFF_H2 + (size_t)NPAIR * HID * 2) // ~152 MB
// big-ws: dedicated w2b so it can be written DURING up (r10-proven present)
#define OFF_W2B2 ((size_t)153 << 20)                // 46.14 MB
#define WS_BIG   ((size_t)200 << 20)

#define GLB(p) ((const __attribute__((address_space(1))) void*)(p))
#define LDS(p) ((__attribute__((address_space(3))) void*)(p))

__device__ __forceinline__ bf16x8 pack8(float4 a, float4 b) {
  bf16x8 v;
  v[0] = (__bf16)a.x; v[1] = (__bf16)a.y; v[2] = (__bf16)a.z; v[3] = (__bf16)a.w;
  v[4] = (__bf16)b.x; v[5] = (__bf16)b.y; v[6] = (__bf16)b.z; v[7] = (__bf16)b.w;
  return v;
}

// ---------------- gating (+ x -> bf16 in fast path) -------------------------
__global__ __launch_bounds__(64) void gate_kernel(
    const float* __restrict__ x, const float* __restrict__ Wg,
    int* __restrict__ counts, int* __restrict__ list, float* __restrict__ wpair,
    __bf16* __restrict__ xb) {
  int t = blockIdx.x;
  int lane = threadIdx.x;
  const float* xp = x + (size_t)t * DIM;
  float xr[16];
#pragma unroll
  for (int i = 0; i < 16; ++i) xr[i] = xp[lane + 64 * i];
  if (xb) {
    __bf16* xo = xb + (size_t)t * DIM;
#pragma unroll
    for (int i = 0; i < 16; ++i) xo[lane + 64 * i] = (__bf16)xr[i];
  }
  float s[NE];
#pragma unroll
  for (int e = 0; e < NE; ++e) {
    const float* wp = Wg + e * DIM;
    float acc = 0.f;
#pragma unroll
    for (int i = 0; i < 16; ++i) acc += xr[i] * wp[lane + 64 * i];
#pragma unroll
    for (int off = 32; off >= 1; off >>= 1) acc += __shfl_xor(acc, off, 64);
    s[e] = acc;
  }
  if (lane == 0) {
    int i0 = 0; float b0 = s[0];
#pragma unroll
    for (int e = 1; e < NE; ++e) if (s[e] > b0) { b0 = s[e]; i0 = e; }
    int i1 = -1; float b1 = -1e30f;
#pragma unroll
    for (int e = 0; e < NE; ++e) if (e != i0 && s[e] > b1) { b1 = s[e]; i1 = e; }
    float e1 = __expf(b1 - b0);
    float w0 = 1.f / (1.f + e1);
    float w1 = e1 * w0;
    int s0 = atomicAdd(&counts[i0], 1);
    list[i0 * CAP + s0] = 2 * t;
    wpair[2 * t] = w0;
    int s1 = atomicAdd(&counts[i1], 1);
    list[i1 * CAP + s1] = 2 * t + 1;
    wpair[2 * t + 1] = w1;
  }
}

// ---------------- fp32 -> bf16 convert: W1 and W3 in one launch -------------
__global__ __launch_bounds__(256) void cvt2_kernel(
    const float* __restrict__ s1, __bf16* __restrict__ d1,
    const float* __restrict__ s3, __bf16* __restrict__ d3) {
  size_t half = (size_t)gridDim.x / 2;
  const float* src;
  __bf16* dst;
  size_t b = blockIdx.x;
  if (b < half) { src = s1; dst = d1; } else { src = s3; dst = d3; b -= half; }
  size_t i = (b * 256 + threadIdx.x) * 8;
  float4 f0 = *(const float4*)(src + i);
  float4 f1 = *(const float4*)(src + i + 4);
  *(bf16x8*)(dst + i) = pack8(f0, f1);
}

// ---------------- fp32 -> bf16 streaming convert (8 elem/thread) ------------
__global__ __launch_bounds__(256) void cvt_kernel(
    const float* __restrict__ src, __bf16* __restrict__ dst) {
  size_t i = (((size_t)blockIdx.x * 256) + threadIdx.x) * 8;
  float4 f0 = *(const float4*)(src + i);
  float4 f1 = *(const float4*)(src + i + 4);
  *(bf16x8*)(dst + i) = pack8(f0, f1);
}

// =============== up10: r9's GEMM (148us proven) + fused W2-cvt role ==========
// GEMM blocks (blockIdx.x < 22): 128x128x64, 4 waves, single-buffered LDS,
// global_load_lds width=16, both-sides XOR chunk swizzle (c ^= row&7),
// N-fastest grid, wpair folded into H epilogue.
// Role blocks (blockIdx.x in [22,24)): W2 fp32 -> w2b, 1024 blocks x 22528
// elems (exact cover) — memory work filling the GEMM's stall bubbles.
__global__ __launch_bounds__(256, 2) void up10_kernel(
    const __bf16* __restrict__ xb, const __bf16* __restrict__ w1b,
    const __bf16* __restrict__ w3b, const int* __restrict__ counts,
    const int* __restrict__ list, const float* __restrict__ wpair,
    __bf16* __restrict__ Hbuf, const float* __restrict__ W2,
    __bf16* __restrict__ w2b) {
  if (blockIdx.x >= NT_UPX) {
    int c = (blockIdx.x - NT_UPX) + 2 * (blockIdx.y + 64 * blockIdx.z);
    size_t base = (size_t)c * 22528;
    int tid = threadIdx.x;
#pragma unroll
    for (int i = 0; i < 11; ++i) {
      size_t off = base + (size_t)i * 2048 + (size_t)tid * 8;
      float4 f0 = *(const float4*)(W2 + off);
      float4 f1 = *(const float4*)(W2 + off + 4);
      *(bf16x8*)(w2b + off) = pack8(f0, f1);
    }
    return;
  }

  int e = blockIdx.z;
  int cnt = counts[e];
  int m0 = blockIdx.y * 128;
  if (m0 >= cnt) return;
  int h0 = blockIdx.x * 128;

  __shared__ __bf16 As[128 * 64];
  __shared__ __bf16 B1s[128 * 64];
  __shared__ __bf16 B3s[128 * 64];

  int tid = threadIdx.x;
  int lane = tid & 63;
  int w = tid >> 6;
  int cl = lane & 15, hi = lane >> 4;
  int wr = w >> 1, wc = w & 1;
  int l8 = lane >> 3, cc = lane & 7;

  const __bf16* asrc[4];
  const __bf16* b1src[4];
  const __bf16* b3src[4];
#pragma unroll
  for (int i = 0; i < 4; ++i) {
    int r = (w * 4 + i) * 8 + l8;
    int csel = (cc ^ (r & 7)) * 8;
    int mrow = m0 + r; if (mrow > cnt - 1) mrow = cnt - 1;
    int p = list[e * CAP + mrow];
    asrc[i]  = xb + (size_t)(p >> 1) * DIM + csel;
    b1src[i] = w1b + ((size_t)e * HID + h0 + r) * DIM + csel;
    b3src[i] = w3b + ((size_t)e * HID + h0 + r) * DIM + csel;
  }

  f32x4 acc1[4][4] = {};
  f32x4 acc3[4][4] = {};

  for (int k0 = 0; k0 < DIM; k0 += 64) {
#pragma unroll
    for (int i = 0; i < 4; ++i) {
      int q = (w * 4 + i) * 1024;
      __builtin_amdgcn_global_load_lds(GLB(asrc[i] + k0),  LDS((char*)As  + q), 16, 0, 0);
      __builtin_amdgcn_global_load_lds(GLB(b1src[i] + k0), LDS((char*)B1s + q), 16, 0, 0);
      __builtin_amdgcn_global_load_lds(GLB(b3src[i] + k0), LDS((char*)B3s + q), 16, 0, 0);
    }
    __syncthreads();
#pragma unroll
    for (int ks = 0; ks < 2; ++ks) {
      int c = hi + ks * 4;
      bf16x8 a[4], bb1[4], bb3[4];
#pragma unroll
      for (int mi = 0; mi < 4; ++mi) {
        int r = wr * 64 + mi * 16 + cl;
        a[mi] = *(const bf16x8*)((const char*)As + r * 128 + ((c ^ (r & 7)) * 16));
      }
#pragma unroll
      for (int ni = 0; ni < 4; ++ni) {
        int r = wc * 64 + ni * 16 + cl;
        bb1[ni] = *(const bf16x8*)((const char*)B1s + r * 128 + ((c ^ (r & 7)) * 16));
        bb3[ni] = *(const bf16x8*)((const char*)B3s + r * 128 + ((c ^ (r & 7)) * 16));
      }
#pragma unroll
      for (int mi = 0; mi < 4; ++mi)
#pragma unroll
        for (int ni = 0; ni < 4; ++ni) {
          acc1[mi][ni] = __builtin_amdgcn_mfma_f32_16x16x32_bf16(a[mi], bb1[ni], acc1[mi][ni], 0, 0, 0);
          acc3[mi][ni] = __builtin_amdgcn_mfma_f32_16x16x32_bf16(a[mi], bb3[ni], acc3[mi][ni], 0, 0, 0);
        }
    }
    __syncthreads();
  }

#pragma unroll
  for (int mi = 0; mi < 4; ++mi) {
#pragma unroll
    for (int rr = 0; rr < 4; ++rr) {
      int m = m0 + wr * 64 + mi * 16 + hi * 4 + rr;
      if (m < cnt) {
        int p = list[e * CAP + m];
        float wgt = wpair[p];
        __bf16* hp = Hbuf + (size_t)p * HID + h0 + wc * 64 + cl;
#pragma unroll
        for (int ni = 0; ni < 4; ++ni) {
          float v1 = acc1[mi][ni][rr], v3 = acc3[mi][ni][rr];
          float gv = (v1 / (1.f + __expf(-v1))) * v3 * wgt;
          hp[ni * 16] = (__bf16)gv;
        }
      }
    }
  }
}

// =============== down9: 128x128x64, XCD-chunked M-fastest (~118us proven) ===
__global__ __launch_bounds__(256, 2) void down9_kernel(
    const __bf16* __restrict__ Hbuf, const __bf16* __restrict__ w2b,
    const int* __restrict__ counts, const int* __restrict__ list,
    __bf16* __restrict__ Obuf) {
  int bid = blockIdx.x;
  int g = (bid & 7) * (NWG_DN / 8) + (bid >> 3);
  int e = g / (NT_DN * MT);
  int rr0 = g % (NT_DN * MT);
  int cnt = counts[e];
  int m0 = (rr0 % MT) * 128;
  if (m0 >= cnt) return;
  int d0 = (rr0 / MT) * 128;

  __shared__ __bf16 As[128 * 64];
  __shared__ __bf16 Bs[128 * 64];

  int tid = threadIdx.x;
  int lane = tid & 63;
  int w = tid >> 6;
  int cl = lane & 15, hi = lane >> 4;
  int wr = w >> 1, wc = w & 1;
  int l8 = lane >> 3, cc = lane & 7;

  const __bf16* asrc[4];
  const __bf16* bsrc[4];
#pragma unroll
  for (int i = 0; i < 4; ++i) {
    int r = (w * 4 + i) * 8 + l8;
    int csel = (cc ^ (r & 7)) * 8;
    int mrow = m0 + r; if (mrow > cnt - 1) mrow = cnt - 1;
    int p = list[e * CAP + mrow];
    asrc[i] = Hbuf + (size_t)p * HID + csel;
    bsrc[i] = w2b + ((size_t)e * DIM + d0 + r) * HID + csel;
  }

  f32x4 acc[4][4] = {};

  for (int k0 = 0; k0 < HID; k0 += 64) {
#pragma unroll
    for (int i = 0; i < 4; ++i) {
      int q = (w * 4 + i) * 1024;
      __builtin_amdgcn_global_load_lds(GLB(asrc[i] + k0), LDS((char*)As + q), 16, 0, 0);
      __builtin_amdgcn_global_load_lds(GLB(bsrc[i] + k0), LDS((char*)Bs + q), 16, 0, 0);
    }
    __syncthreads();
#pragma unroll
    for (int ks = 0; ks < 2; ++ks) {
      int c = hi + ks * 4;
      bf16x8 a[4], b[4];
#pragma unroll
      for (int mi = 0; mi < 4; ++mi) {
        int r = wr * 64 + mi * 16 + cl;
        a[mi] = *(const bf16x8*)((const char*)As + r * 128 + ((c ^ (r & 7)) * 16));
      }
#pragma unroll
      for (int ni = 0; ni < 4; ++ni) {
        int r = wc * 64 + ni * 16 + cl;
        b[ni] = *(const bf16x8*)((const char*)Bs + r * 128 + ((c ^ (r & 7)) * 16));
      }
#pragma unroll
      for (int mi = 0; mi < 4; ++mi)
#pragma unroll
        for (int ni = 0; ni < 4; ++ni)
          acc[mi][ni] = __builtin_amdgcn_mfma_f32_16x16x32_bf16(a[mi], b[ni], acc[mi][ni], 0, 0, 0);
    }
    __syncthreads();
  }

#pragma unroll
  for (int mi = 0; mi < 4; ++mi) {
#pragma unroll
    for (int rr = 0; rr < 4; ++rr) {
      int m = m0 + wr * 64 + mi * 16 + hi * 4 + rr;
      if (m < cnt) {
        int p = list[e * CAP + m];
        __bf16* op = Obuf + (size_t)p * DIM + d0 + wc * 64 + cl;
#pragma unroll
        for (int ni = 0; ni < 4; ++ni)
          op[ni * 16] = (__bf16)acc[mi][ni][rr];
      }
    }
  }
}

// ---------------- combine: out[t] = Obuf[2t] + Obuf[2t+1] -------------------
__global__ __launch_bounds__(256) void combine_kernel(
    const __bf16* __restrict__ Obuf, float* __restrict__ out) {
  size_t j = (((size_t)blockIdx.x * 256) + threadIdx.x) * 8;
  size_t t = j >> 10;
  bf16x8 a = *(const bf16x8*)(Obuf + j + t * DIM);
  bf16x8 b = *(const bf16x8*)(Obuf + j + t * DIM + DIM);
  float4 o0, o1;
  o0.x = (float)a[0] + (float)b[0]; o0.y = (float)a[1] + (float)b[1];
  o0.z = (float)a[2] + (float)b[2]; o0.w = (float)a[3] + (float)b[3];
  o1.x = (float)a[4] + (float)b[4]; o1.y = (float)a[5] + (float)b[5];
  o1.z = (float)a[6] + (float)b[6]; o1.w = (float)a[7] + (float)b[7];
  *(float4*)(out + j) = o0;
  *(float4*)(out + j + 4) = o1;
}

// =============== fallback path (round-1 kernels) ============================
__device__ __forceinline__ void cvt_store16(__bf16* dst, const float* src) {
#pragma unroll
  for (int j = 0; j < 2; ++j) {
    float4 f0 = *(const float4*)(src + j * 8);
    float4 f1 = *(const float4*)(src + j * 8 + 4);
    *(bf16x8*)(dst + j * 8) = pack8(f0, f1);
  }
}

__global__ __launch_bounds__(256) void up_kernel(
    const float* __restrict__ x, const float* __restrict__ W1,
    const float* __restrict__ W3, const int* __restrict__ counts,
    const int* __restrict__ list, __bf16* __restrict__ Hbuf) {
  int e = blockIdx.z;
  int cnt = counts[e];
  int m0 = blockIdx.y * 64;
  if (m0 >= cnt) return;
  int h0 = blockIdx.x * 64;

  __shared__ __bf16 As[64][72];
  __shared__ __bf16 B1s[64][72];
  __shared__ __bf16 B3s[64][72];

  int tid = threadIdx.x;
  int r = tid >> 2;
  int cs = (tid & 3) * 16;

  const float* asrc = nullptr;
  int mrow = m0 + r;
  if (mrow < cnt) {
    int p = list[e * CAP + mrow];
    asrc = x + (size_t)(p >> 1) * DIM;
  }
  const float* b1src = W1 + ((size_t)e * HID + (h0 + r)) * DIM;
  const float* b3src = W3 + ((size_t)e * HID + (h0 + r)) * DIM;

  int lane = tid & 63;
  int w = tid >> 6;
  int wr = w >> 1, wc = w & 1;
  int cl = lane & 15, hi = lane >> 4;

  f32x4 acc1[2][2] = {};
  f32x4 acc3[2][2] = {};

  for (int k0 = 0; k0 < DIM; k0 += 64) {
    if (asrc) {
      cvt_store16(&As[r][cs], asrc + k0 + cs);
    } else {
      bf16x8 z = {};
      *(bf16x8*)&As[r][cs] = z;
      *(bf16x8*)&As[r][cs + 8] = z;
    }
    cvt_store16(&B1s[r][cs], b1src + k0 + cs);
    cvt_store16(&B3s[r][cs], b3src + k0 + cs);
    __syncthreads();
#pragma unroll
    for (int ks = 0; ks < 64; ks += 32) {
      bf16x8 a[2], b1f[2], b3f[2];
#pragma unroll
      for (int mi = 0; mi < 2; ++mi)
        a[mi] = *(const bf16x8*)&As[wr * 32 + mi * 16 + cl][ks + hi * 8];
#pragma unroll
      for (int ni = 0; ni < 2; ++ni) {
        b1f[ni] = *(const bf16x8*)&B1s[wc * 32 + ni * 16 + cl][ks + hi * 8];
        b3f[ni] = *(const bf16x8*)&B3s[wc * 32 + ni * 16 + cl][ks + hi * 8];
      }
#pragma unroll
      for (int mi = 0; mi < 2; ++mi)
#pragma unroll
        for (int ni = 0; ni < 2; ++ni) {
          acc1[mi][ni] = __builtin_amdgcn_mfma_f32_16x16x32_bf16(a[mi], b1f[ni], acc1[mi][ni], 0, 0, 0);
          acc3[mi][ni] = __builtin_amdgcn_mfma_f32_16x16x32_bf16(a[mi], b3f[ni], acc3[mi][ni], 0, 0, 0);
        }
    }
    __syncthreads();
  }

#pragma unroll
  for (int mi = 0; mi < 2; ++mi) {
#pragma unroll
    for (int rr = 0; rr < 4; ++rr) {
      int m = m0 + wr * 32 + mi * 16 + hi * 4 + rr;
      if (m < cnt) {
        int p = list[e * CAP + m];
        __bf16* hp = Hbuf + (size_t)p * HID + h0 + wc * 32 + cl;
#pragma unroll
        for (int ni = 0; ni < 2; ++ni) {
          float v1 = acc1[mi][ni][rr], v3 = acc3[mi][ni][rr];
          float gg = (v1 / (1.f + __expf(-v1))) * v3;
          hp[ni * 16] = (__bf16)gg;
        }
      }
    }
  }
}

__global__ __launch_bounds__(256) void down_kernel(
    const __bf16* __restrict__ Hbuf, const float* __restrict__ W2,
    const int* __restrict__ counts, const int* __restrict__ list,
    const float* __restrict__ wpair, float* __restrict__ out) {
  int e = blockIdx.z;
  int cnt = counts[e];
  int m0 = blockIdx.y * 64;
  if (m0 >= cnt) return;
  int d0 = blockIdx.x * 64;

  __shared__ __bf16 As[64][72];
  __shared__ __bf16 Bs[64][72];

  int tid = threadIdx.x;
  int r = tid >> 2;
  int cs = (tid & 3) * 16;

  const __bf16* asrc = nullptr;
  int mrow = m0 + r;
  if (mrow < cnt) {
    int p = list[e * CAP + mrow];
    asrc = Hbuf + (size_t)p * HID;
  }
  const float* bsrc = W2 + ((size_t)e * DIM + (d0 + r)) * HID;

  int lane = tid & 63;
  int w = tid >> 6;
  int wr = w >> 1, wc = w & 1;
  int cl = lane & 15, hi = lane >> 4;

  f32x4 acc[2][2] = {};

  for (int k0 = 0; k0 < HID; k0 += 64) {
    if (asrc) {
      *(bf16x8*)&As[r][cs]     = *(const bf16x8*)(asrc + k0 + cs);
      *(bf16x8*)&As[r][cs + 8] = *(const bf16x8*)(asrc + k0 + cs + 8);
    } else {
      bf16x8 z = {};
      *(bf16x8*)&As[r][cs] = z;
      *(bf16x8*)&As[r][cs + 8] = z;
    }
    cvt_store16(&Bs[r][cs], bsrc + k0 + cs);
    __syncthreads();
#pragma unroll
    for (int ks = 0; ks < 64; ks += 32) {
      bf16x8 a[2], b[2];
#pragma unroll
      for (int mi = 0; mi < 2; ++mi)
        a[mi] = *(const bf16x8*)&As[wr * 32 + mi * 16 + cl][ks + hi * 8];
#pragma unroll
      for (int ni = 0; ni < 2; ++ni)
        b[ni] = *(const bf16x8*)&Bs[wc * 32 + ni * 16 + cl][ks + hi * 8];
#pragma unroll
      for (int mi = 0; mi < 2; ++mi)
#pragma unroll
        for (int ni = 0; ni < 2; ++ni)
          acc[mi][ni] = __builtin_amdgcn_mfma_f32_16x16x32_bf16(a[mi], b[ni], acc[mi][ni], 0, 0, 0);
    }
    __syncthreads();
  }

#pragma unroll
  for (int mi = 0; mi < 2; ++mi) {
#pragma unroll
    for (int rr = 0; rr < 4; ++rr) {
      int m = m0 + wr * 32 + mi * 16 + hi * 4 + rr;
      if (m < cnt) {
        int p = list[e * CAP + m];
        int t = p >> 1;
        float wgt = wpair[p];
        float* op = out + (size_t)t * DIM + d0 + wc * 32 + cl;
#pragma unroll
        for (int ni = 0; ni < 2; ++ni)
          atomicAdd(&op[ni * 16], wgt * acc[mi][ni][rr]);
      }
    }
  }
}

extern "C" void kernel_launch(void* const* d_in, const int* in_sizes, int n_in,
                              void* d_out, int out_size, void* d_ws, size_t ws_size,
                              hipStream_t stream) {
  const float* x  = (const float*)d_in[0];
  const float* Wg = (const float*)d_in[1];
  const float* W1 = (const float*)d_in[2];
  const float* W3 = (const float*)d_in[3];
  const float* W2 = (const float*)d_in[4];
  float* out = (float*)d_out;

  char* ws = (char*)d_ws;
  int* counts  = (int*)(ws + OFF_CNT);
  int* list    = (int*)(ws + OFF_LIST);
  float* wpair = (float*)(ws + OFF_WP);

  hipMemsetAsync(counts, 0, 64, stream);

  if (ws_size >= WS_NEED) {
    __bf16* xb   = (__bf16*)(ws + OFF_XB);
    __bf16* w1b  = (__bf16*)(ws + OFF_W1B);
    __bf16* w3b  = (__bf16*)(ws + OFF_W3B);
    __bf16* Hbuf = (__bf16*)(ws + OFF_H2);
    __bf16* Obuf = (__bf16*)(ws + OFF_W3B);   // reuse after up

    gate_kernel<<<NTOK, 64, 0, stream>>>(x, Wg, counts, list, wpair, xb);

    cvt2_kernel<<<2 * (WELEM / 2048), 256, 0, stream>>>(W1, w1b, W3, w3b);

    if (ws_size >= WS_BIG) {
      // single-variable round: fused W2-cvt rides inside up (dedicated w2b)
      __bf16* w2b = (__bf16*)(ws + OFF_W2B2);
      up10_kernel<<<dim3(NT_UPX + 2, CAP / 128, NE), 256, 0, stream>>>(
          xb, w1b, w3b, counts, list, wpair, Hbuf, W2, w2b);
      down9_kernel<<<NWG_DN, 256, 0, stream>>>(Hbuf, w2b, counts, list, Obuf);
    } else {
      up10_kernel<<<dim3(NT_UPX, CAP / 128, NE), 256, 0, stream>>>(
          xb, w1b, w3b, counts, list, wpair, Hbuf, W2, nullptr);
      cvt_kernel<<<WELEM / 2048, 256, 0, stream>>>(W2, w1b);
      down9_kernel<<<NWG_DN, 256, 0, stream>>>(Hbuf, w1b, counts, list, Obuf);
    }

    combine_kernel<<<NTOK * DIM / 2048, 256, 0, stream>>>(Obuf, out);
  } else {
    hipMemsetAsync(d_out, 0, (size_t)out_size * sizeof(float), stream);
    __bf16* Hbuf = (__bf16*)(ws + OFF_H1);
    gate_kernel<<<NTOK, 64, 0, stream>>>(x, Wg, counts, list, wpair, nullptr);
    up_kernel<<<dim3(HID / 64, CAP / 64, NE), 256, 0, stream>>>(x, W1, W3, counts, list, Hbuf);
    down_kernel<<<dim3(DIM / 64, CAP / 64, NE), 256, 0, stream>>>(Hbuf, W2, counts, list, wpair, out);
  }
}

// Round 16
// 366.155 us; speedup vs baseline: 1.0553x; 1.0553x over previous
//
#include <hip/hip_runtime.h>
#include <hip/hip_bf16.h>

#define DIM  1024
#define HID  2816
#define NE   8
#define NTOK 4096
#define NPAIR 8192
#define CAP  8192

#define NT_DN (DIM / 128)           // 8 N-tiles (down)
#define MT    (CAP / 128)           // 64 M-tiles
#define NWG_DN (NE * NT_DN * MT)    // 4096

#define WELEM ((size_t)NE * DIM * HID)
#define NWG_CVT (WELEM / 2048)      // 11264 blocks per weight tensor
#define NWG_GATE (NTOK / 4)         // 1024 gate-role blocks (4 tokens/block)

typedef __bf16 bf16x8 __attribute__((ext_vector_type(8)));
typedef float f32x4 __attribute__((ext_vector_type(4)));

// ---------------- workspace layout (r9/r14-proven) ----------------
#define OFF_CNT  0                         // 8 ints
#define OFF_LIST 1024                      // NE*CAP ints  = 256 KB
#define OFF_WP   (OFF_LIST + NE*CAP*4)     // NPAIR floats = 32 KB
// fallback path
#define OFF_H1   (OFF_WP + NPAIR*4)
// fast path
#define OFF_XB   ((size_t)1 << 20)                  // 8 MB   (NTOK*DIM bf16)
#define OFF_W1B  ((size_t)10 << 20)                 // 46.14 MB; reused for W2b after up
#define OFF_W3B  ((size_t)57 << 20)                 // 46.14 MB; reused for Obuf after up
#define OFF_H2   ((size_t)106 << 20)                // 46.14 MB (NPAIR*HID bf16)
#define WS_NEED  (OFF_H2 + (size_t)NPAIR * HID * 2) // ~152 MB

#define GLB(p) ((const __attribute__((address_space(1))) void*)(p))
#define LDS(p) ((__attribute__((address_space(3))) void*)(p))

__device__ __forceinline__ bf16x8 pack8(float4 a, float4 b) {
  bf16x8 v;
  v[0] = (__bf16)a.x; v[1] = (__bf16)a.y; v[2] = (__bf16)a.z; v[3] = (__bf16)a.w;
  v[4] = (__bf16)b.x; v[5] = (__bf16)b.y; v[6] = (__bf16)b.z; v[7] = (__bf16)b.w;
  return v;
}

// =============== prep: gate roles + W1/W3 cvt roles in ONE launch ===========
// Gate blocks (blockIdx < 1024): 4 tokens/block, one 64-lane wave per token
// (shfl stays wave-local). Cvt blocks: W1 then W3, 8 elem/thread (r9-proven).
// The two roles are data-independent; both complete before up9 launches.
__global__ __launch_bounds__(256) void prep_kernel(
    const float* __restrict__ x, const float* __restrict__ Wg,
    int* __restrict__ counts, int* __restrict__ list, float* __restrict__ wpair,
    __bf16* __restrict__ xb,
    const float* __restrict__ W1, __bf16* __restrict__ w1b,
    const float* __restrict__ W3, __bf16* __restrict__ w3b) {
  if (blockIdx.x < NWG_GATE) {
    int t = blockIdx.x * 4 + (threadIdx.x >> 6);
    int lane = threadIdx.x & 63;
    const float* xp = x + (size_t)t * DIM;
    float xr[16];
#pragma unroll
    for (int i = 0; i < 16; ++i) xr[i] = xp[lane + 64 * i];
    __bf16* xo = xb + (size_t)t * DIM;
#pragma unroll
    for (int i = 0; i < 16; ++i) xo[lane + 64 * i] = (__bf16)xr[i];
    float s[NE];
#pragma unroll
    for (int e = 0; e < NE; ++e) {
      const float* wp = Wg + e * DIM;
      float acc = 0.f;
#pragma unroll
      for (int i = 0; i < 16; ++i) acc += xr[i] * wp[lane + 64 * i];
#pragma unroll
      for (int off = 32; off >= 1; off >>= 1) acc += __shfl_xor(acc, off, 64);
      s[e] = acc;
    }
    if (lane == 0) {
      int i0 = 0; float b0 = s[0];
#pragma unroll
      for (int e = 1; e < NE; ++e) if (s[e] > b0) { b0 = s[e]; i0 = e; }
      int i1 = -1; float b1 = -1e30f;
#pragma unroll
      for (int e = 0; e < NE; ++e) if (e != i0 && s[e] > b1) { b1 = s[e]; i1 = e; }
      float e1 = __expf(b1 - b0);
      float w0 = 1.f / (1.f + e1);
      float w1 = e1 * w0;
      int s0 = atomicAdd(&counts[i0], 1);
      list[i0 * CAP + s0] = 2 * t;
      wpair[2 * t] = w0;
      int s1 = atomicAdd(&counts[i1], 1);
      list[i1 * CAP + s1] = 2 * t + 1;
      wpair[2 * t + 1] = w1;
    }
    return;
  }
  size_t b = blockIdx.x - NWG_GATE;
  const float* src; __bf16* dst;
  if (b < NWG_CVT) { src = W1; dst = w1b; } else { src = W3; dst = w3b; b -= NWG_CVT; }
  size_t i = (b * 256 + threadIdx.x) * 8;
  float4 f0 = *(const float4*)(src + i);
  float4 f1 = *(const float4*)(src + i + 4);
  *(bf16x8*)(dst + i) = pack8(f0, f1);
}

// ---------------- fp32 -> bf16 streaming convert (8 elem/thread) ------------
__global__ __launch_bounds__(256) void cvt_kernel(
    const float* __restrict__ src, __bf16* __restrict__ dst) {
  size_t i = (((size_t)blockIdx.x * 256) + threadIdx.x) * 8;
  float4 f0 = *(const float4*)(src + i);
  float4 f1 = *(const float4*)(src + i + 4);
  *(bf16x8*)(dst + i) = pack8(f0, f1);
}

// ---------------- standalone gate (fallback path) ---------------------------
__global__ __launch_bounds__(64) void gate_kernel(
    const float* __restrict__ x, const float* __restrict__ Wg,
    int* __restrict__ counts, int* __restrict__ list, float* __restrict__ wpair) {
  int t = blockIdx.x;
  int lane = threadIdx.x;
  const float* xp = x + (size_t)t * DIM;
  float xr[16];
#pragma unroll
  for (int i = 0; i < 16; ++i) xr[i] = xp[lane + 64 * i];
  float s[NE];
#pragma unroll
  for (int e = 0; e < NE; ++e) {
    const float* wp = Wg + e * DIM;
    float acc = 0.f;
#pragma unroll
    for (int i = 0; i < 16; ++i) acc += xr[i] * wp[lane + 64 * i];
#pragma unroll
    for (int off = 32; off >= 1; off >>= 1) acc += __shfl_xor(acc, off, 64);
    s[e] = acc;
  }
  if (lane == 0) {
    int i0 = 0; float b0 = s[0];
#pragma unroll
    for (int e = 1; e < NE; ++e) if (s[e] > b0) { b0 = s[e]; i0 = e; }
    int i1 = -1; float b1 = -1e30f;
#pragma unroll
    for (int e = 0; e < NE; ++e) if (e != i0 && s[e] > b1) { b1 = s[e]; i1 = e; }
    float e1 = __expf(b1 - b0);
    float w0 = 1.f / (1.f + e1);
    float w1 = e1 * w0;
    int s0 = atomicAdd(&counts[i0], 1);
    list[i0 * CAP + s0] = 2 * t;
    wpair[2 * t] = w0;
    int s1 = atomicAdd(&counts[i1], 1);
    list[i1 * CAP + s1] = 2 * t + 1;
    wpair[2 * t + 1] = w1;
  }
}

// =============== up9: 128x128x64, 4 waves, single-buffered (148us proven) ===
__global__ __launch_bounds__(256, 2) void up9_kernel(
    const __bf16* __restrict__ xb, const __bf16* __restrict__ w1b,
    const __bf16* __restrict__ w3b, const int* __restrict__ counts,
    const int* __restrict__ list, const float* __restrict__ wpair,
    __bf16* __restrict__ Hbuf) {
  int e = blockIdx.z;
  int cnt = counts[e];
  int m0 = blockIdx.y * 128;
  if (m0 >= cnt) return;
  int h0 = blockIdx.x * 128;

  __shared__ __bf16 As[128 * 64];
  __shared__ __bf16 B1s[128 * 64];
  __shared__ __bf16 B3s[128 * 64];

  int tid = threadIdx.x;
  int lane = tid & 63;
  int w = tid >> 6;
  int cl = lane & 15, hi = lane >> 4;
  int wr = w >> 1, wc = w & 1;
  int l8 = lane >> 3, cc = lane & 7;

  const __bf16* asrc[4];
  const __bf16* b1src[4];
  const __bf16* b3src[4];
#pragma unroll
  for (int i = 0; i < 4; ++i) {
    int r = (w * 4 + i) * 8 + l8;
    int csel = (cc ^ (r & 7)) * 8;
    int mrow = m0 + r; if (mrow > cnt - 1) mrow = cnt - 1;
    int p = list[e * CAP + mrow];
    asrc[i]  = xb + (size_t)(p >> 1) * DIM + csel;
    b1src[i] = w1b + ((size_t)e * HID + h0 + r) * DIM + csel;
    b3src[i] = w3b + ((size_t)e * HID + h0 + r) * DIM + csel;
  }

  f32x4 acc1[4][4] = {};
  f32x4 acc3[4][4] = {};

  for (int k0 = 0; k0 < DIM; k0 += 64) {
#pragma unroll
    for (int i = 0; i < 4; ++i) {
      int q = (w * 4 + i) * 1024;
      __builtin_amdgcn_global_load_lds(GLB(asrc[i] + k0),  LDS((char*)As  + q), 16, 0, 0);
      __builtin_amdgcn_global_load_lds(GLB(b1src[i] + k0), LDS((char*)B1s + q), 16, 0, 0);
      __builtin_amdgcn_global_load_lds(GLB(b3src[i] + k0), LDS((char*)B3s + q), 16, 0, 0);
    }
    __syncthreads();
#pragma unroll
    for (int ks = 0; ks < 2; ++ks) {
      int c = hi + ks * 4;
      bf16x8 a[4], bb1[4], bb3[4];
#pragma unroll
      for (int mi = 0; mi < 4; ++mi) {
        int r = wr * 64 + mi * 16 + cl;
        a[mi] = *(const bf16x8*)((const char*)As + r * 128 + ((c ^ (r & 7)) * 16));
      }
#pragma unroll
      for (int ni = 0; ni < 4; ++ni) {
        int r = wc * 64 + ni * 16 + cl;
        bb1[ni] = *(const bf16x8*)((const char*)B1s + r * 128 + ((c ^ (r & 7)) * 16));
        bb3[ni] = *(const bf16x8*)((const char*)B3s + r * 128 + ((c ^ (r & 7)) * 16));
      }
#pragma unroll
      for (int mi = 0; mi < 4; ++mi)
#pragma unroll
        for (int ni = 0; ni < 4; ++ni) {
          acc1[mi][ni] = __builtin_amdgcn_mfma_f32_16x16x32_bf16(a[mi], bb1[ni], acc1[mi][ni], 0, 0, 0);
          acc3[mi][ni] = __builtin_amdgcn_mfma_f32_16x16x32_bf16(a[mi], bb3[ni], acc3[mi][ni], 0, 0, 0);
        }
    }
    __syncthreads();
  }

#pragma unroll
  for (int mi = 0; mi < 4; ++mi) {
#pragma unroll
    for (int rr = 0; rr < 4; ++rr) {
      int m = m0 + wr * 64 + mi * 16 + hi * 4 + rr;
      if (m < cnt) {
        int p = list[e * CAP + m];
        float wgt = wpair[p];
        __bf16* hp = Hbuf + (size_t)p * HID + h0 + wc * 64 + cl;
#pragma unroll
        for (int ni = 0; ni < 4; ++ni) {
          float v1 = acc1[mi][ni][rr], v3 = acc3[mi][ni][rr];
          float gv = (v1 / (1.f + __expf(-v1))) * v3 * wgt;
          hp[ni * 16] = (__bf16)gv;
        }
      }
    }
  }
}

// =============== down14: 128x128x64, XCD-chunked M-fastest (r14-proven) =====
__global__ __launch_bounds__(256, 3) void down14_kernel(
    const __bf16* __restrict__ Hbuf, const __bf16* __restrict__ w2b,
    const int* __restrict__ counts, const int* __restrict__ list,
    __bf16* __restrict__ Obuf) {
  int bid = blockIdx.x;
  int g = (bid & 7) * (NWG_DN / 8) + (bid >> 3);
  int e = g / (NT_DN * MT);
  int rr0 = g % (NT_DN * MT);
  int cnt = counts[e];
  int m0 = (rr0 % MT) * 128;
  if (m0 >= cnt) return;
  int d0 = (rr0 / MT) * 128;

  __shared__ __bf16 As[128 * 64];
  __shared__ __bf16 Bs[128 * 64];

  int tid = threadIdx.x;
  int lane = tid & 63;
  int w = tid >> 6;
  int cl = lane & 15, hi = lane >> 4;
  int wr = w >> 1, wc = w & 1;
  int l8 = lane >> 3, cc = lane & 7;

  const __bf16* asrc[4];
  const __bf16* bsrc[4];
#pragma unroll
  for (int i = 0; i < 4; ++i) {
    int r = (w * 4 + i) * 8 + l8;
    int csel = (cc ^ (r & 7)) * 8;
    int mrow = m0 + r; if (mrow > cnt - 1) mrow = cnt - 1;
    int p = list[e * CAP + mrow];
    asrc[i] = Hbuf + (size_t)p * HID + csel;
    bsrc[i] = w2b + ((size_t)e * DIM + d0 + r) * HID + csel;
  }

  f32x4 acc[4][4] = {};

  for (int k0 = 0; k0 < HID; k0 += 64) {
#pragma unroll
    for (int i = 0; i < 4; ++i) {
      int q = (w * 4 + i) * 1024;
      __builtin_amdgcn_global_load_lds(GLB(asrc[i] + k0), LDS((char*)As + q), 16, 0, 0);
      __builtin_amdgcn_global_load_lds(GLB(bsrc[i] + k0), LDS((char*)Bs + q), 16, 0, 0);
    }
    __syncthreads();
#pragma unroll
    for (int ks = 0; ks < 2; ++ks) {
      int c = hi + ks * 4;
      bf16x8 a[4], b[4];
#pragma unroll
      for (int mi = 0; mi < 4; ++mi) {
        int r = wr * 64 + mi * 16 + cl;
        a[mi] = *(const bf16x8*)((const char*)As + r * 128 + ((c ^ (r & 7)) * 16));
      }
#pragma unroll
      for (int ni = 0; ni < 4; ++ni) {
        int r = wc * 64 + ni * 16 + cl;
        b[ni] = *(const bf16x8*)((const char*)Bs + r * 128 + ((c ^ (r & 7)) * 16));
      }
#pragma unroll
      for (int mi = 0; mi < 4; ++mi)
#pragma unroll
        for (int ni = 0; ni < 4; ++ni)
          acc[mi][ni] = __builtin_amdgcn_mfma_f32_16x16x32_bf16(a[mi], b[ni], acc[mi][ni], 0, 0, 0);
    }
    __syncthreads();
  }

#pragma unroll
  for (int mi = 0; mi < 4; ++mi) {
#pragma unroll
    for (int rr = 0; rr < 4; ++rr) {
      int m = m0 + wr * 64 + mi * 16 + hi * 4 + rr;
      if (m < cnt) {
        int p = list[e * CAP + m];
        __bf16* op = Obuf + (size_t)p * DIM + d0 + wc * 64 + cl;
#pragma unroll
        for (int ni = 0; ni < 4; ++ni)
          op[ni * 16] = (__bf16)acc[mi][ni][rr];
      }
    }
  }
}

// ---------------- combine: out[t] = Obuf[2t] + Obuf[2t+1] -------------------
__global__ __launch_bounds__(256) void combine_kernel(
    const __bf16* __restrict__ Obuf, float* __restrict__ out) {
  size_t j = (((size_t)blockIdx.x * 256) + threadIdx.x) * 8;
  size_t t = j >> 10;
  bf16x8 a = *(const bf16x8*)(Obuf + j + t * DIM);
  bf16x8 b = *(const bf16x8*)(Obuf + j + t * DIM + DIM);
  float4 o0, o1;
  o0.x = (float)a[0] + (float)b[0]; o0.y = (float)a[1] + (float)b[1];
  o0.z = (float)a[2] + (float)b[2]; o0.w = (float)a[3] + (float)b[3];
  o1.x = (float)a[4] + (float)b[4]; o1.y = (float)a[5] + (float)b[5];
  o1.z = (float)a[6] + (float)b[6]; o1.w = (float)a[7] + (float)b[7];
  *(float4*)(out + j) = o0;
  *(float4*)(out + j + 4) = o1;
}

// =============== fallback path (round-1 kernels) ============================
__device__ __forceinline__ void cvt_store16(__bf16* dst, const float* src) {
#pragma unroll
  for (int j = 0; j < 2; ++j) {
    float4 f0 = *(const float4*)(src + j * 8);
    float4 f1 = *(const float4*)(src + j * 8 + 4);
    *(bf16x8*)(dst + j * 8) = pack8(f0, f1);
  }
}

__global__ __launch_bounds__(256) void up_kernel(
    const float* __restrict__ x, const float* __restrict__ W1,
    const float* __restrict__ W3, const int* __restrict__ counts,
    const int* __restrict__ list, __bf16* __restrict__ Hbuf) {
  int e = blockIdx.z;
  int cnt = counts[e];
  int m0 = blockIdx.y * 64;
  if (m0 >= cnt) return;
  int h0 = blockIdx.x * 64;

  __shared__ __bf16 As[64][72];
  __shared__ __bf16 B1s[64][72];
  __shared__ __bf16 B3s[64][72];

  int tid = threadIdx.x;
  int r = tid >> 2;
  int cs = (tid & 3) * 16;

  const float* asrc = nullptr;
  int mrow = m0 + r;
  if (mrow < cnt) {
    int p = list[e * CAP + mrow];
    asrc = x + (size_t)(p >> 1) * DIM;
  }
  const float* b1src = W1 + ((size_t)e * HID + (h0 + r)) * DIM;
  const float* b3src = W3 + ((size_t)e * HID + (h0 + r)) * DIM;

  int lane = tid & 63;
  int w = tid >> 6;
  int wr = w >> 1, wc = w & 1;
  int cl = lane & 15, hi = lane >> 4;

  f32x4 acc1[2][2] = {};
  f32x4 acc3[2][2] = {};

  for (int k0 = 0; k0 < DIM; k0 += 64) {
    if (asrc) {
      cvt_store16(&As[r][cs], asrc + k0 + cs);
    } else {
      bf16x8 z = {};
      *(bf16x8*)&As[r][cs] = z;
      *(bf16x8*)&As[r][cs + 8] = z;
    }
    cvt_store16(&B1s[r][cs], b1src + k0 + cs);
    cvt_store16(&B3s[r][cs], b3src + k0 + cs);
    __syncthreads();
#pragma unroll
    for (int ks = 0; ks < 64; ks += 32) {
      bf16x8 a[2], b1f[2], b3f[2];
#pragma unroll
      for (int mi = 0; mi < 2; ++mi)
        a[mi] = *(const bf16x8*)&As[wr * 32 + mi * 16 + cl][ks + hi * 8];
#pragma unroll
      for (int ni = 0; ni < 2; ++ni) {
        b1f[ni] = *(const bf16x8*)&B1s[wc * 32 + ni * 16 + cl][ks + hi * 8];
        b3f[ni] = *(const bf16x8*)&B3s[wc * 32 + ni * 16 + cl][ks + hi * 8];
      }
#pragma unroll
      for (int mi = 0; mi < 2; ++mi)
#pragma unroll
        for (int ni = 0; ni < 2; ++ni) {
          acc1[mi][ni] = __builtin_amdgcn_mfma_f32_16x16x32_bf16(a[mi], b1f[ni], acc1[mi][ni], 0, 0, 0);
          acc3[mi][ni] = __builtin_amdgcn_mfma_f32_16x16x32_bf16(a[mi], b3f[ni], acc3[mi][ni], 0, 0, 0);
        }
    }
    __syncthreads();
  }

#pragma unroll
  for (int mi = 0; mi < 2; ++mi) {
#pragma unroll
    for (int rr = 0; rr < 4; ++rr) {
      int m = m0 + wr * 32 + mi * 16 + hi * 4 + rr;
      if (m < cnt) {
        int p = list[e * CAP + m];
        __bf16* hp = Hbuf + (size_t)p * HID + h0 + wc * 32 + cl;
#pragma unroll
        for (int ni = 0; ni < 2; ++ni) {
          float v1 = acc1[mi][ni][rr], v3 = acc3[mi][ni][rr];
          float gg = (v1 / (1.f + __expf(-v1))) * v3;
          hp[ni * 16] = (__bf16)gg;
        }
      }
    }
  }
}

__global__ __launch_bounds__(256) void down_kernel(
    const __bf16* __restrict__ Hbuf, const float* __restrict__ W2,
    const int* __restrict__ counts, const int* __restrict__ list,
    const float* __restrict__ wpair, float* __restrict__ out) {
  int e = blockIdx.z;
  int cnt = counts[e];
  int m0 = blockIdx.y * 64;
  if (m0 >= cnt) return;
  int d0 = blockIdx.x * 64;

  __shared__ __bf16 As[64][72];
  __shared__ __bf16 Bs[64][72];

  int tid = threadIdx.x;
  int r = tid >> 2;
  int cs = (tid & 3) * 16;

  const __bf16* asrc = nullptr;
  int mrow = m0 + r;
  if (mrow < cnt) {
    int p = list[e * CAP + mrow];
    asrc = Hbuf + (size_t)p * HID;
  }
  const float* bsrc = W2 + ((size_t)e * DIM + (d0 + r)) * HID;

  int lane = tid & 63;
  int w = tid >> 6;
  int wr = w >> 1, wc = w & 1;
  int cl = lane & 15, hi = lane >> 4;

  f32x4 acc[2][2] = {};

  for (int k0 = 0; k0 < HID; k0 += 64) {
    if (asrc) {
      *(bf16x8*)&As[r][cs]     = *(const bf16x8*)(asrc + k0 + cs);
      *(bf16x8*)&As[r][cs + 8] = *(const bf16x8*)(asrc + k0 + cs + 8);
    } else {
      bf16x8 z = {};
      *(bf16x8*)&As[r][cs] = z;
      *(bf16x8*)&As[r][cs + 8] = z;
    }
    cvt_store16(&Bs[r][cs], bsrc + k0 + cs);
    __syncthreads();
#pragma unroll
    for (int ks = 0; ks < 64; ks += 32) {
      bf16x8 a[2], b[2];
#pragma unroll
      for (int mi = 0; mi < 2; ++mi)
        a[mi] = *(const bf16x8*)&As[wr * 32 + mi * 16 + cl][ks + hi * 8];
#pragma unroll
      for (int ni = 0; ni < 2; ++ni)
        b[ni] = *(const bf16x8*)&Bs[wc * 32 + ni * 16 + cl][ks + hi * 8];
#pragma unroll
      for (int mi = 0; mi < 2; ++mi)
#pragma unroll
        for (int ni = 0; ni < 2; ++ni)
          acc[mi][ni] = __builtin_amdgcn_mfma_f32_16x16x32_bf16(a[mi], b[ni], acc[mi][ni], 0, 0, 0);
    }
    __syncthreads();
  }

#pragma unroll
  for (int mi = 0; mi < 2; ++mi) {
#pragma unroll
    for (int rr = 0; rr < 4; ++rr) {
      int m = m0 + wr * 32 + mi * 16 + hi * 4 + rr;
      if (m < cnt) {
        int p = list[e * CAP + m];
        int t = p >> 1;
        float wgt = wpair[p];
        float* op = out + (size_t)t * DIM + d0 + wc * 32 + cl;
#pragma unroll
        for (int ni = 0; ni < 2; ++ni)
          atomicAdd(&op[ni * 16], wgt * acc[mi][ni][rr]);
      }
    }
  }
}

extern "C" void kernel_launch(void* const* d_in, const int* in_sizes, int n_in,
                              void* d_out, int out_size, void* d_ws, size_t ws_size,
                              hipStream_t stream) {
  const float* x  = (const float*)d_in[0];
  const float* Wg = (const float*)d_in[1];
  const float* W1 = (const float*)d_in[2];
  const float* W3 = (const float*)d_in[3];
  const float* W2 = (const float*)d_in[4];
  float* out = (float*)d_out;

  char* ws = (char*)d_ws;
  int* counts  = (int*)(ws + OFF_CNT);
  int* list    = (int*)(ws + OFF_LIST);
  float* wpair = (float*)(ws + OFF_WP);

  hipMemsetAsync(counts, 0, 64, stream);

  if (ws_size >= WS_NEED) {
    __bf16* xb   = (__bf16*)(ws + OFF_XB);
    __bf16* w1b  = (__bf16*)(ws + OFF_W1B);   // reused for W2b after up
    __bf16* w3b  = (__bf16*)(ws + OFF_W3B);   // reused for Obuf after up
    __bf16* Hbuf = (__bf16*)(ws + OFF_H2);
    __bf16* Obuf = (__bf16*)(ws + OFF_W3B);

    prep_kernel<<<NWG_GATE + 2 * NWG_CVT, 256, 0, stream>>>(
        x, Wg, counts, list, wpair, xb, W1, w1b, W3, w3b);

    up9_kernel<<<dim3(HID / 128, CAP / 128, NE), 256, 0, stream>>>(
        xb, w1b, w3b, counts, list, wpair, Hbuf);

    cvt_kernel<<<NWG_CVT, 256, 0, stream>>>(W2, w1b);

    down14_kernel<<<NWG_DN, 256, 0, stream>>>(Hbuf, w1b, counts, list, Obuf);

    combine_kernel<<<NTOK * DIM / 2048, 256, 0, stream>>>(Obuf, out);
  } else {
    hipMemsetAsync(d_out, 0, (size_t)out_size * sizeof(float), stream);
    __bf16* Hbuf = (__bf16*)(ws + OFF_H1);
    gate_kernel<<<NTOK, 64, 0, stream>>>(x, Wg, counts, list, wpair);
    up_kernel<<<dim3(HID / 64, CAP / 64, NE), 256, 0, stream>>>(x, W1, W3, counts, list, Hbuf);
    down_kernel<<<dim3(DIM / 64, CAP / 64, NE), 256, 0, stream>>>(Hbuf, W2, counts, list, wpair, out);
  }
}